// Round 5
// baseline (232.624 us; speedup 1.0000x reference)
//
#include <hip/hip_runtime.h>
#include <math.h>

#define EMB 256

typedef _Float16 half8 __attribute__((ext_vector_type(8)));
typedef float f32x4 __attribute__((ext_vector_type(4)));

// ---------- async global->LDS (16B/lane) ----------
__device__ __forceinline__ void gload_lds16(const void* gsrc, void* lds) {
    __builtin_amdgcn_global_load_lds(
        (const __attribute__((address_space(1))) void*)gsrc,
        (__attribute__((address_space(3))) void*)lds,
        16, 0, 0);
}

// Pre-split layout: for each row m of a [rows][256] f32 matrix, emit 512 halfs:
//   dst[m*512 + c*64 + g'*8 .. +8) = granule g of chunk c, where
//   c = k/32 (8 chunks), g = part*4 + seg (part: 0=hi,1=lo; seg = (k/8)&3),
//   g' = g ^ (m&7)   <- bank swizzle baked into GLOBAL layout so the GEMM can
//                       global_load_lds linearly and ds_read conflict-free.
__global__ void presplit(const float* __restrict__ X,
                         const float* __restrict__ Wh, const float* __restrict__ Wt,
                         _Float16* __restrict__ Xs, _Float16* __restrict__ Whs,
                         _Float16* __restrict__ Wts, int M)
{
    const int total = (M + 512) * 32;          // granules of 8 f32
    for (int g = blockIdx.x * 256 + threadIdx.x; g < total; g += gridDim.x * 256) {
        const int m = g >> 5;                  // virtual row
        const int cs = g & 31;                 // c*4 + seg
        const int c = cs >> 2, seg = cs & 3;

        const float* src; _Float16* dst; int r;
        if (m < M)            { src = X;  dst = Xs;  r = m; }
        else if (m < M + 256) { src = Wh; dst = Whs; r = m - M; }
        else                  { src = Wt; dst = Wts; r = m - M - 256; }

        const float* s = src + (size_t)r * EMB + c * 32 + seg * 8;
        const float4 v0 = *(const float4*)s;
        const float4 v1 = *(const float4*)(s + 4);
        const float f[8] = {v0.x, v0.y, v0.z, v0.w, v1.x, v1.y, v1.z, v1.w};
        half8 hi, lo;
#pragma unroll
        for (int i = 0; i < 8; ++i) {
            hi[i] = (_Float16)f[i];
            lo[i] = (_Float16)(f[i] - (float)hi[i]);
        }
        _Float16* d = dst + (size_t)r * 512 + c * 64;
        const int sw = r & 7;
        *(half8*)(d + ((seg     ^ sw) << 3)) = hi;
        *(half8*)(d + (((4 + seg) ^ sw) << 3)) = lo;
    }
}

// GEMM from pre-split operands. OUT = X*W^T + b via hi*hi + hi*lo + lo*hi.
// blockIdx.x: bit0 = n-block (0/128), bit1 = head/tail. Tile 128x128, 4 waves,
// wave tile 64x64 of 16x16x32 f16 MFMA. LDS staged by global_load_lds dwordx4
// (linear dest; swizzle lives in the global layout). 2-barrier m97 structure.
__global__ __launch_bounds__(256, 2)
void gemm_f16_3term(const _Float16* __restrict__ Xs,
                    const _Float16* __restrict__ Whs, const _Float16* __restrict__ Wts,
                    const float* __restrict__ bh, const float* __restrict__ bt,
                    float* __restrict__ Hout, float* __restrict__ Tout, int M)
{
    __shared__ __align__(16) _Float16 Abuf[128 * 64];   // 16 KB: 128 rows x 128B chunk
    __shared__ __align__(16) _Float16 Bbuf[128 * 64];   // 16 KB

    const int tid = threadIdx.x;
    const int sel = blockIdx.x >> 1;
    const int n0  = (blockIdx.x & 1) << 7;
    const int m0  = blockIdx.y << 7;
    const _Float16* __restrict__ Ws = sel ? Wts : Whs;
    const float* __restrict__ bias  = sel ? bt : bh;
    float* __restrict__ OUT         = sel ? Tout : Hout;

    const int lane = tid & 63;
    const int wv = tid >> 6;
    const int wm = (wv >> 1) << 6;
    const int wn = (wv & 1) << 6;
    const int l15 = lane & 15, l4 = lane >> 4;

    // staging: issue i covers rows 32i..32i+31; thread -> row (tid>>3), granule (tid&7)
    const int srow = tid >> 3;          // 0..31
    const int sgr  = tid & 7;
    const char* abase = (const char*)Xs + (size_t)m0 * 1024;
    const char* bbase = (const char*)Ws + (size_t)n0 * 1024;

    f32x4 acc[4][4];
#pragma unroll
    for (int i = 0; i < 4; ++i)
#pragma unroll
        for (int j = 0; j < 4; ++j) acc[i][j] = (f32x4){0.f, 0.f, 0.f, 0.f};

    for (int c = 0; c < 8; ++c) {
        if (c) __syncthreads();     // all frag reads of prev chunk done
#pragma unroll
        for (int i = 0; i < 4; ++i) {
            const int row = i * 32 + srow;
            const int off = row * 128 + sgr * 16;
            gload_lds16(abase + (size_t)row * 1024 + c * 128 + sgr * 16, (char*)Abuf + off);
            gload_lds16(bbase + (size_t)row * 1024 + c * 128 + sgr * 16, (char*)Bbuf + off);
        }
        __syncthreads();            // drains vmcnt(0): staged data visible

        half8 ah[4], al[4];
#pragma unroll
        for (int f = 0; f < 4; ++f) {
            const int row = wm + f * 16 + l15;
            const char* rb = (const char*)Abuf + row * 128;
            ah[f] = *(const half8*)(rb + ((l4       ^ (row & 7)) << 4));
            al[f] = *(const half8*)(rb + (((4 + l4) ^ (row & 7)) << 4));
        }
#pragma unroll
        for (int j = 0; j < 4; ++j) {
            const int n = wn + j * 16 + l15;
            const char* rb = (const char*)Bbuf + n * 128;
            const half8 bhf = *(const half8*)(rb + ((l4       ^ (n & 7)) << 4));
            const half8 blf = *(const half8*)(rb + (((4 + l4) ^ (n & 7)) << 4));
#pragma unroll
            for (int i = 0; i < 4; ++i) {
                acc[i][j] = __builtin_amdgcn_mfma_f32_16x16x32_f16(ah[i], bhf, acc[i][j], 0, 0, 0);
                acc[i][j] = __builtin_amdgcn_mfma_f32_16x16x32_f16(ah[i], blf, acc[i][j], 0, 0, 0);
                acc[i][j] = __builtin_amdgcn_mfma_f32_16x16x32_f16(al[i], bhf, acc[i][j], 0, 0, 0);
            }
        }
    }

    // epilogue: C/D layout col = lane&15, row = (lane>>4)*4 + reg (m89)
#pragma unroll
    for (int i = 0; i < 4; ++i) {
        const int rbase = m0 + wm + i * 16 + l4 * 4;
#pragma unroll
        for (int rg = 0; rg < 4; ++rg) {
            const int gr = rbase + rg;
            if (gr < M) {
                float* dst = &OUT[(size_t)gr * EMB + n0 + wn];
#pragma unroll
                for (int j = 0; j < 4; ++j) {
                    const int col = j * 16 + l15;
                    dst[col] = acc[i][j][rg] + bias[n0 + wn + col];
                }
            }
        }
    }
}

// ---------- round-4 fallback GEMM (in-loop split), used if ws is small ----------
typedef _Float16 half4v __attribute__((ext_vector_type(4)));
__device__ __forceinline__ void split2(const float4 v, half4v& hi, half4v& lo) {
    hi[0] = (_Float16)v.x; hi[1] = (_Float16)v.y;
    hi[2] = (_Float16)v.z; hi[3] = (_Float16)v.w;
    lo[0] = (_Float16)(v.x - (float)hi[0]);
    lo[1] = (_Float16)(v.y - (float)hi[1]);
    lo[2] = (_Float16)(v.z - (float)hi[2]);
    lo[3] = (_Float16)(v.w - (float)hi[3]);
}

__global__ __launch_bounds__(256, 2)
void gemm_split_mfma(const float* __restrict__ X,
                     const float* __restrict__ Wh, const float* __restrict__ bh,
                     const float* __restrict__ Wt, const float* __restrict__ bt,
                     float* __restrict__ Hout, float* __restrict__ Tout, int M)
{
    __shared__ __align__(16) _Float16 Ab[128 * 64];
    __shared__ __align__(16) _Float16 Bb[128 * 64];

    const int tid = threadIdx.x;
    const int sel = blockIdx.x >> 1;
    const int n0  = (blockIdx.x & 1) << 7;
    const int m0  = blockIdx.y << 7;
    const float* __restrict__ Wsel = sel ? Wt : Wh;
    const float* __restrict__ bsel = sel ? bt : bh;
    float* __restrict__ OUT = sel ? Tout : Hout;

    const int lane = tid & 63;
    const int wv = tid >> 6;
    const int wm = (wv >> 1) << 6;
    const int wn = (wv & 1) << 6;
    const int l15 = lane & 15, l4 = lane >> 4;

    const int q    = tid & 7;
    const int srow = tid >> 3;
    const int ghi  = q >> 1;
    const int wby  = (q & 1) << 3;

    f32x4 acc[4][4];
#pragma unroll
    for (int i = 0; i < 4; ++i)
#pragma unroll
        for (int j = 0; j < 4; ++j) acc[i][j] = (f32x4){0.f, 0.f, 0.f, 0.f};

    float4 xg[4], wg[4];
#pragma unroll
    for (int p = 0; p < 4; ++p) {
        const int r = srow + p * 32;
        const int gm = m0 + r;
        xg[p] = (gm < M) ? *(const float4*)&X[(size_t)gm * EMB + q * 4]
                         : make_float4(0.f, 0.f, 0.f, 0.f);
        wg[p] = *(const float4*)&Wsel[(size_t)(n0 + r) * EMB + q * 4];
    }

    for (int k0 = 0; k0 < EMB; k0 += 32) {
        __syncthreads();
#pragma unroll
        for (int p = 0; p < 4; ++p) {
            const int r = srow + p * 32;
            const int r7 = r & 7;
            half4v hi, lo;
            split2(xg[p], hi, lo);
            char* ab = (char*)Ab + r * 128 + wby;
            *(half4v*)(ab + (((ghi    ) ^ r7) << 4)) = hi;
            *(half4v*)(ab + (((ghi + 4) ^ r7) << 4)) = lo;
            split2(wg[p], hi, lo);
            char* bb = (char*)Bb + r * 128 + wby;
            *(half4v*)(bb + (((ghi    ) ^ r7) << 4)) = hi;
            *(half4v*)(bb + (((ghi + 4) ^ r7) << 4)) = lo;
        }
        __syncthreads();

        if (k0 + 32 < EMB) {
            const int kn = k0 + 32 + q * 4;
#pragma unroll
            for (int p = 0; p < 4; ++p) {
                const int r = srow + p * 32;
                const int gm = m0 + r;
                xg[p] = (gm < M) ? *(const float4*)&X[(size_t)gm * EMB + kn]
                                 : make_float4(0.f, 0.f, 0.f, 0.f);
                wg[p] = *(const float4*)&Wsel[(size_t)(n0 + r) * EMB + kn];
            }
        }

        half8 ah[4], al[4];
#pragma unroll
        for (int f = 0; f < 4; ++f) {
            const int m = wm + f * 16 + l15;
            const char* ar = (const char*)Ab + m * 128;
            ah[f] = *(const half8*)(ar + (((l4    ) ^ (m & 7)) << 4));
            al[f] = *(const half8*)(ar + (((l4 + 4) ^ (m & 7)) << 4));
        }
#pragma unroll
        for (int j = 0; j < 4; ++j) {
            const int n = wn + j * 16 + l15;
            const char* br = (const char*)Bb + n * 128;
            const half8 bhv = *(const half8*)(br + (((l4    ) ^ (n & 7)) << 4));
            const half8 blv = *(const half8*)(br + (((l4 + 4) ^ (n & 7)) << 4));
#pragma unroll
            for (int i = 0; i < 4; ++i) {
                acc[i][j] = __builtin_amdgcn_mfma_f32_16x16x32_f16(ah[i], bhv, acc[i][j], 0, 0, 0);
                acc[i][j] = __builtin_amdgcn_mfma_f32_16x16x32_f16(ah[i], blv, acc[i][j], 0, 0, 0);
                acc[i][j] = __builtin_amdgcn_mfma_f32_16x16x32_f16(al[i], bhv, acc[i][j], 0, 0, 0);
            }
        }
    }

#pragma unroll
    for (int i = 0; i < 4; ++i) {
        const int rbase = m0 + wm + i * 16 + l4 * 4;
#pragma unroll
        for (int rg = 0; rg < 4; ++rg) {
            const int gr = rbase + rg;
            if (gr < M) {
                float* dst = &OUT[(size_t)gr * EMB + n0 + wn];
#pragma unroll
                for (int j = 0; j < 4; ++j) {
                    const int col = j * 16 + l15;
                    dst[col] = acc[i][j][rg] + bsel[n0 + wn + col];
                }
            }
        }
    }
}

// One wave per edge: gather H[src], T[dst], rel[type], triple-product reduce, sigmoid.
__global__ __launch_bounds__(256)
void edge_score(const float* __restrict__ H, const float* __restrict__ T,
                const float* __restrict__ rel, const int* __restrict__ ei,
                const int* __restrict__ et, float* __restrict__ out, int E)
{
    const int lane = threadIdx.x & 63;
    const int wid = threadIdx.x >> 6;
    const int e = blockIdx.x * 4 + wid;
    if (e >= E) return;

    const int src = ei[e];
    const int dst = ei[E + e];
    const int r = et[e];

    const float4 h = *(const float4*)&H[(size_t)src * EMB + lane * 4];
    const float4 t = *(const float4*)&T[(size_t)dst * EMB + lane * 4];
    const float4 g = *(const float4*)&rel[(size_t)r * EMB + lane * 4];

    float s = h.x * g.x * t.x + h.y * g.y * t.y + h.z * g.z * t.z + h.w * g.w * t.w;
#pragma unroll
    for (int off = 32; off > 0; off >>= 1)
        s += __shfl_xor(s, off, 64);

    if (lane == 0) out[e] = 1.0f / (1.0f + expf(-s));
}

// Last-resort fallback: one block per edge, direct fp32 matvecs.
__global__ __launch_bounds__(256)
void edge_direct(const float* __restrict__ X, const int* __restrict__ ei,
                 const int* __restrict__ et,
                 const float* __restrict__ Wh, const float* __restrict__ bh,
                 const float* __restrict__ Wt, const float* __restrict__ bt,
                 const float* __restrict__ rel, float* __restrict__ out, int E)
{
    __shared__ float xsrc[EMB], xdst[EMB];
    __shared__ float red[256];
    const int e = blockIdx.x;
    const int tid = threadIdx.x;
    const int src = ei[e], dst = ei[E + e], r = et[e];

    xsrc[tid] = X[(size_t)src * EMB + tid];
    xdst[tid] = X[(size_t)dst * EMB + tid];
    __syncthreads();

    float ah = 0.f, at = 0.f;
    const float* wh = Wh + (size_t)tid * EMB;
    const float* wt = Wt + (size_t)tid * EMB;
#pragma unroll 8
    for (int k = 0; k < EMB; k += 4) {
        float4 w4 = *(const float4*)&wh[k];
        ah += w4.x * xsrc[k] + w4.y * xsrc[k + 1] + w4.z * xsrc[k + 2] + w4.w * xsrc[k + 3];
        float4 v4 = *(const float4*)&wt[k];
        at += v4.x * xdst[k] + v4.y * xdst[k + 1] + v4.z * xdst[k + 2] + v4.w * xdst[k + 3];
    }
    red[tid] = (ah + bh[tid]) * rel[(size_t)r * EMB + tid] * (at + bt[tid]);
    __syncthreads();
    for (int s2 = 128; s2 > 0; s2 >>= 1) {
        if (tid < s2) red[tid] += red[tid + s2];
        __syncthreads();
    }
    if (tid == 0) out[e] = 1.0f / (1.0f + expf(-red[0]));
}

extern "C" void kernel_launch(void* const* d_in, const int* in_sizes, int n_in,
                              void* d_out, int out_size, void* d_ws, size_t ws_size,
                              hipStream_t stream) {
    const float* x   = (const float*)d_in[0];
    const int*   ei  = (const int*)d_in[1];
    const int*   et  = (const int*)d_in[2];
    const float* Wh  = (const float*)d_in[3];
    const float* bh  = (const float*)d_in[4];
    const float* Wt  = (const float*)d_in[5];
    const float* bt  = (const float*)d_in[6];
    const float* rel = (const float*)d_in[7];
    float* out = (float*)d_out;

    const int M = in_sizes[0] / EMB;   // 100000 nodes
    const int E = in_sizes[2];         // 250000 edges

    const size_t szHT = (size_t)2 * M * EMB * sizeof(float);           // H + T
    const size_t szXs = (size_t)M * 512 * sizeof(_Float16);            // pre-split X
    const size_t szWs = (size_t)2 * 256 * 512 * sizeof(_Float16);      // Whs + Wts
    const size_t need_full = szHT + szXs + szWs;

    if (ws_size >= need_full) {
        float* H = (float*)d_ws;
        float* T = H + (size_t)M * EMB;
        _Float16* Xs  = (_Float16*)((char*)d_ws + szHT);
        _Float16* Whs = Xs + (size_t)M * 512;
        _Float16* Wts = Whs + (size_t)256 * 512;

        presplit<<<2048, 256, 0, stream>>>(x, Wh, Wt, Xs, Whs, Wts, M);
        dim3 grid(4, (M + 127) / 128);
        gemm_f16_3term<<<grid, 256, 0, stream>>>(Xs, Whs, Wts, bh, bt, H, T, M);
        edge_score<<<(E + 3) / 4, 256, 0, stream>>>(H, T, rel, ei, et, out, E);
    } else if (ws_size >= szHT) {
        float* H = (float*)d_ws;
        float* T = H + (size_t)M * EMB;
        dim3 grid(4, (M + 127) / 128);
        gemm_split_mfma<<<grid, 256, 0, stream>>>(x, Wh, bh, Wt, bt, H, T, M);
        edge_score<<<(E + 3) / 4, 256, 0, stream>>>(H, T, rel, ei, et, out, E);
    } else {
        edge_direct<<<E, 256, 0, stream>>>(x, ei, et, Wh, bh, Wt, bt, rel, out, E);
    }
}

// Round 6
// 204.597 us; speedup vs baseline: 1.1370x; 1.1370x over previous
//
#include <hip/hip_runtime.h>
#include <math.h>

#define EMB 256

typedef _Float16 half8 __attribute__((ext_vector_type(8)));
typedef float f32x4 __attribute__((ext_vector_type(4)));

// ---------- async global->LDS, 16B per lane ----------
__device__ __forceinline__ void gload_lds16(const void* gsrc, void* lds) {
    __builtin_amdgcn_global_load_lds(
        (const __attribute__((address_space(1))) void*)gsrc,
        (__attribute__((address_space(3))) void*)lds,
        16, 0, 0);
}

// 8 f32 (two LDS f32x4 reads) -> hi/lo fp16 split: x ~= hi + lo to ~2^-22 rel.
__device__ __forceinline__ void split8(const f32x4 a, const f32x4 b,
                                       half8& hi, half8& lo) {
#pragma unroll
    for (int i = 0; i < 4; ++i) {
        hi[i]     = (_Float16)a[i];
        lo[i]     = (_Float16)(a[i] - (float)hi[i]);
        hi[4 + i] = (_Float16)b[i];
        lo[4 + i] = (_Float16)(b[i] - (float)hi[4 + i]);
    }
}

// Dual-output GEMM: one block computes a 128x128 tile of BOTH
//   H = X*Wh^T + bh  and  T = X*Wt^T + bt   (3-term split-f16 MFMA:
//   hi*hi + hi*lo + lo*hi; lo*lo ~2^-22 dropped).
// Tiles staged f32 by global_load_lds (linear LDS dest). The 16B-granule
// XOR swizzle (g' = g ^ (row&7)) is baked into the per-lane GLOBAL source
// address (m173 pattern), so ds_read_b128 frag reads are uniform 8 lanes
// per granule-column = conflict-free optimum.
// Grid: flat nwg = 2 * ceil(M/128); bijective XCD swizzle (m204) keeps the
// 2 n-variants of an m-tile + consecutive m-tiles on one XCD's L2 ->
// X slab fetched from HBM once.
__global__ __launch_bounds__(256, 2)
void gemm_dual(const float* __restrict__ X,
               const float* __restrict__ Wh, const float* __restrict__ bh,
               const float* __restrict__ Wt, const float* __restrict__ bt,
               float* __restrict__ Hout, float* __restrict__ Tout,
               int M, int nwg)
{
    __shared__ __align__(16) float Af [128 * 32];   // 16 KB, rows of 128 B
    __shared__ __align__(16) float Bhf[128 * 32];   // 16 KB
    __shared__ __align__(16) float Btf[128 * 32];   // 16 KB

    // bijective XCD swizzle: xcd = flat&7 gets a contiguous wg chunk
    const int fl = blockIdx.x;
    const int q = nwg >> 3, r = nwg & 7;
    const int xcd = fl & 7, ix = fl >> 3;
    const int wg = (xcd < r) ? xcd * (q + 1) + ix
                             : r * (q + 1) + (xcd - r) * q + ix;
    const int n0 = (wg & 1) << 7;      // 0 or 128
    const int m0 = (wg >> 1) << 7;     // m-tile * 128

    const int tid = threadIdx.x;
    const int lane = tid & 63;
    const int wv = tid >> 6;
    const int wm = (wv >> 1) << 6;     // 0 / 64
    const int wn = (wv & 1) << 6;      // 0 / 64
    const int l15 = lane & 15, l4 = lane >> 4;

    // frag-read byte offsets: logical granules 2*l4, 2*l4+1 of row, XOR row&7
    const int s  = l15 & 7;            // (frag row) & 7 == l15 & 7
    const int ga = (((l4 << 1) ^ s) << 4);
    const int gb = ga ^ 16;

    // staging: thread -> (row = tid>>3 (+32i), phys granule g' = tid&7);
    // source granule g = g' ^ (row&7) baked into global address
    const int srow = tid >> 3;
    const int sg   = tid & 7;
    const int swg  = (sg ^ (srow & 7)) << 4;   // global byte offset in 128B chunk
    const int sldo = srow * 128 + sg * 16;     // linear LDS byte offset (== tid*16)

    f32x4 accH[4][4], accT[4][4];
#pragma unroll
    for (int i = 0; i < 4; ++i)
#pragma unroll
        for (int j = 0; j < 4; ++j) {
            accH[i][j] = (f32x4){0.f, 0.f, 0.f, 0.f};
            accT[i][j] = (f32x4){0.f, 0.f, 0.f, 0.f};
        }

    for (int c = 0; c < 8; ++c) {
        if (c) __syncthreads();        // prev chunk's frag reads done
        const int cb = c << 7;         // chunk byte offset within 1KB row
#pragma unroll
        for (int i = 0; i < 4; ++i) {
            const int row = srow + (i << 5);
            const int gm = m0 + row;
            const int gmc = gm < M ? gm : M - 1;   // clamp; rows >=M never stored
            const int ldso = sldo + (i << 12);     // + i*32*128
            gload_lds16((const char*)X  + (size_t)gmc * 1024 + cb + swg,
                        (char*)Af + ldso);
            gload_lds16((const char*)Wh + (size_t)(n0 + row) * 1024 + cb + swg,
                        (char*)Bhf + ldso);
            gload_lds16((const char*)Wt + (size_t)(n0 + row) * 1024 + cb + swg,
                        (char*)Btf + ldso);
        }
        __syncthreads();               // drains vmcnt: staged data visible

        half8 ahh[4], ahl[4];
#pragma unroll
        for (int fi = 0; fi < 4; ++fi) {
            const char* ar = (const char*)Af + (wm + fi * 16 + l15) * 128;
            split8(*(const f32x4*)(ar + ga), *(const f32x4*)(ar + gb),
                   ahh[fi], ahl[fi]);
        }
#pragma unroll
        for (int j = 0; j < 4; ++j) {
            const int nrow = (wn + j * 16 + l15) * 128;
            half8 bhh, bhl, bth, btl;
            {
                const char* hr = (const char*)Bhf + nrow;
                split8(*(const f32x4*)(hr + ga), *(const f32x4*)(hr + gb), bhh, bhl);
                const char* tr = (const char*)Btf + nrow;
                split8(*(const f32x4*)(tr + ga), *(const f32x4*)(tr + gb), bth, btl);
            }
#pragma unroll
            for (int i = 0; i < 4; ++i) {
                accH[i][j] = __builtin_amdgcn_mfma_f32_16x16x32_f16(ahh[i], bhh, accH[i][j], 0, 0, 0);
                accH[i][j] = __builtin_amdgcn_mfma_f32_16x16x32_f16(ahh[i], bhl, accH[i][j], 0, 0, 0);
                accH[i][j] = __builtin_amdgcn_mfma_f32_16x16x32_f16(ahl[i], bhh, accH[i][j], 0, 0, 0);
                accT[i][j] = __builtin_amdgcn_mfma_f32_16x16x32_f16(ahh[i], bth, accT[i][j], 0, 0, 0);
                accT[i][j] = __builtin_amdgcn_mfma_f32_16x16x32_f16(ahh[i], btl, accT[i][j], 0, 0, 0);
                accT[i][j] = __builtin_amdgcn_mfma_f32_16x16x32_f16(ahl[i], bth, accT[i][j], 0, 0, 0);
            }
        }
    }

    // epilogue: C/D layout col = lane&15, row = (lane>>4)*4 + reg (m89)
    float bhv[4], btv[4];
#pragma unroll
    for (int j = 0; j < 4; ++j) {
        bhv[j] = bh[n0 + wn + j * 16 + l15];
        btv[j] = bt[n0 + wn + j * 16 + l15];
    }
#pragma unroll
    for (int i = 0; i < 4; ++i) {
        const int rbase = m0 + wm + i * 16 + l4 * 4;
#pragma unroll
        for (int rg = 0; rg < 4; ++rg) {
            const int gr = rbase + rg;
            if (gr < M) {
                float* dh = &Hout[(size_t)gr * EMB + n0 + wn];
                float* dt = &Tout[(size_t)gr * EMB + n0 + wn];
#pragma unroll
                for (int j = 0; j < 4; ++j) {
                    const int col = j * 16 + l15;
                    dh[col] = accH[i][j][rg] + bhv[j];
                    dt[col] = accT[i][j][rg] + btv[j];
                }
            }
        }
    }
}

// One wave per edge: gather H[src], T[dst], rel[type], triple-product reduce, sigmoid.
__global__ __launch_bounds__(256)
void edge_score(const float* __restrict__ H, const float* __restrict__ T,
                const float* __restrict__ rel, const int* __restrict__ ei,
                const int* __restrict__ et, float* __restrict__ out, int E)
{
    const int lane = threadIdx.x & 63;
    const int wid = threadIdx.x >> 6;
    const int e = blockIdx.x * 4 + wid;
    if (e >= E) return;

    const int src = ei[e];
    const int dst = ei[E + e];
    const int r = et[e];

    const float4 h = *(const float4*)&H[(size_t)src * EMB + lane * 4];
    const float4 t = *(const float4*)&T[(size_t)dst * EMB + lane * 4];
    const float4 g = *(const float4*)&rel[(size_t)r * EMB + lane * 4];

    float s = h.x * g.x * t.x + h.y * g.y * t.y + h.z * g.z * t.z + h.w * g.w * t.w;
#pragma unroll
    for (int off = 32; off > 0; off >>= 1)
        s += __shfl_xor(s, off, 64);

    if (lane == 0) out[e] = 1.0f / (1.0f + expf(-s));
}

// Last-resort fallback: one block per edge, direct fp32 matvecs.
__global__ __launch_bounds__(256)
void edge_direct(const float* __restrict__ X, const int* __restrict__ ei,
                 const int* __restrict__ et,
                 const float* __restrict__ Wh, const float* __restrict__ bh,
                 const float* __restrict__ Wt, const float* __restrict__ bt,
                 const float* __restrict__ rel, float* __restrict__ out, int E)
{
    __shared__ float xsrc[EMB], xdst[EMB];
    __shared__ float red[256];
    const int e = blockIdx.x;
    const int tid = threadIdx.x;
    const int src = ei[e], dst = ei[E + e], r = et[e];

    xsrc[tid] = X[(size_t)src * EMB + tid];
    xdst[tid] = X[(size_t)dst * EMB + tid];
    __syncthreads();

    float ah = 0.f, at = 0.f;
    const float* wh = Wh + (size_t)tid * EMB;
    const float* wt = Wt + (size_t)tid * EMB;
#pragma unroll 8
    for (int k = 0; k < EMB; k += 4) {
        float4 w4 = *(const float4*)&wh[k];
        ah += w4.x * xsrc[k] + w4.y * xsrc[k + 1] + w4.z * xsrc[k + 2] + w4.w * xsrc[k + 3];
        float4 v4 = *(const float4*)&wt[k];
        at += v4.x * xdst[k] + v4.y * xdst[k + 1] + v4.z * xdst[k + 2] + v4.w * xdst[k + 3];
    }
    red[tid] = (ah + bh[tid]) * rel[(size_t)r * EMB + tid] * (at + bt[tid]);
    __syncthreads();
    for (int s2 = 128; s2 > 0; s2 >>= 1) {
        if (tid < s2) red[tid] += red[tid + s2];
        __syncthreads();
    }
    if (tid == 0) out[e] = 1.0f / (1.0f + expf(-red[0]));
}

extern "C" void kernel_launch(void* const* d_in, const int* in_sizes, int n_in,
                              void* d_out, int out_size, void* d_ws, size_t ws_size,
                              hipStream_t stream) {
    const float* x   = (const float*)d_in[0];
    const int*   ei  = (const int*)d_in[1];
    const int*   et  = (const int*)d_in[2];
    const float* Wh  = (const float*)d_in[3];
    const float* bh  = (const float*)d_in[4];
    const float* Wt  = (const float*)d_in[5];
    const float* bt  = (const float*)d_in[6];
    const float* rel = (const float*)d_in[7];
    float* out = (float*)d_out;

    const int M = in_sizes[0] / EMB;   // 100000 nodes
    const int E = in_sizes[2];         // 250000 edges

    const size_t szHT = (size_t)2 * M * EMB * sizeof(float);   // H + T

    if (ws_size >= szHT) {
        float* H = (float*)d_ws;
        float* T = H + (size_t)M * EMB;
        const int mtiles = (M + 127) / 128;
        const int nwg = 2 * mtiles;
        gemm_dual<<<nwg, 256, 0, stream>>>(x, Wh, bh, Wt, bt, H, T, M, nwg);
        edge_score<<<(E + 3) / 4, 256, 0, stream>>>(H, T, rel, ei, et, out, E);
    } else {
        edge_direct<<<E, 256, 0, stream>>>(x, ei, et, Wh, bh, Wt, bt, rel, out, E);
    }
}

// Round 7
// 179.405 us; speedup vs baseline: 1.2966x; 1.1404x over previous
//
#include <hip/hip_runtime.h>
#include <math.h>

#define EMB 256

typedef _Float16 half8 __attribute__((ext_vector_type(8)));
typedef float f32x4 __attribute__((ext_vector_type(4)));

// ---------- async global->LDS, 16B per lane ----------
__device__ __forceinline__ void gload_lds16(const void* gsrc, void* lds) {
    __builtin_amdgcn_global_load_lds(
        (const __attribute__((address_space(1))) void*)gsrc,
        (__attribute__((address_space(3))) void*)lds,
        16, 0, 0);
}

// 8 f32 -> hi/lo fp16 split: x ~= hi + lo to ~2^-22 rel.
__device__ __forceinline__ void split8(const f32x4 a, const f32x4 b,
                                       half8& hi, half8& lo) {
#pragma unroll
    for (int i = 0; i < 4; ++i) {
        hi[i]     = (_Float16)a[i];
        lo[i]     = (_Float16)(a[i] - (float)hi[i]);
        hi[4 + i] = (_Float16)b[i];
        lo[4 + i] = (_Float16)(b[i] - (float)hi[4 + i]);
    }
}

// Pre-split W (Wh,Wt: 256x256 f32 each) into granule-swizzled f16 hi/lo:
// dst[r*512 + c*64 + g'*8 ..+8) where g = part*4+seg, g' = g ^ (r&7).
// Total 16384 granules -> 64 blocks x 256 threads.
__global__ void presplit_w(const float* __restrict__ Wh, const float* __restrict__ Wt,
                           _Float16* __restrict__ Whs, _Float16* __restrict__ Wts)
{
    const int g = blockIdx.x * 256 + threadIdx.x;
    const int m = g >> 5;                  // 0..511
    const int cs = g & 31;
    const int c = cs >> 2, seg = cs & 3;
    const float* src = (m < 256) ? Wh : Wt;
    _Float16* dst    = (m < 256) ? Whs : Wts;
    const int r = m & 255;

    const float* s = src + (size_t)r * EMB + c * 32 + seg * 8;
    const f32x4 v0 = *(const f32x4*)s;
    const f32x4 v1 = *(const f32x4*)(s + 4);
    half8 hi, lo;
    split8(v0, v1, hi, lo);
    _Float16* d = dst + (size_t)r * 512 + c * 64;
    const int sw = r & 7;
    *(half8*)(d + ((seg       ^ sw) << 3)) = hi;
    *(half8*)(d + (((4 + seg) ^ sw) << 3)) = lo;
}

// Dual-output GEMM: one block -> 128x128 tile of BOTH H = X*Wh^T + bh and
// T = X*Wt^T + bt. 3-term split-f16 MFMA (hi*hi + hi*lo + lo*hi).
// A: staged global->reg->split->ds_write f16 (split once per block).
// B: pre-split f16 in global, staged by global_load_lds (zero in-loop VALU).
// Granule-XOR swizzle (g^=row&7) on all LDS layouts -> frag ds_read_b128
// uniform 8 lanes/granule-column = conflict-free optimum.
__global__ __launch_bounds__(256, 2)
void gemm_dual(const float* __restrict__ X,
               const _Float16* __restrict__ Whs, const _Float16* __restrict__ Wts,
               const float* __restrict__ bh, const float* __restrict__ bt,
               float* __restrict__ Hout, float* __restrict__ Tout,
               int M, int nwg)
{
    __shared__ __align__(16) _Float16 Ax[128 * 64];   // 16 KB (hi g0-3, lo g4-7)
    __shared__ __align__(16) _Float16 Bh[128 * 64];   // 16 KB
    __shared__ __align__(16) _Float16 Bt[128 * 64];   // 16 KB

    // bijective XCD swizzle (m204)
    const int fl = blockIdx.x;
    const int q = nwg >> 3, r = nwg & 7;
    const int xcd = fl & 7, ix = fl >> 3;
    const int wg = (xcd < r) ? xcd * (q + 1) + ix
                             : r * (q + 1) + (xcd - r) * q + ix;
    const int n0 = (wg & 1) << 7;
    const int m0 = (wg >> 1) << 7;

    const int tid = threadIdx.x;
    const int lane = tid & 63;
    const int wv = tid >> 6;
    const int wm = (wv >> 1) << 6;
    const int wn = (wv & 1) << 6;
    const int l15 = lane & 15, l4 = lane >> 4;

    // ---- A staging mapping: thread -> (row = tid>>1, 16-float half = tid&1)
    const int ar = tid >> 1;
    const int ahalf = tid & 1;
    const int gmA = m0 + ar;
    const float* aSrc = X + (size_t)(gmA < M ? gmA : M - 1) * EMB + ahalf * 16;
    char* aDst = (char*)Ax + ar * 128;
    const int ar7 = ar & 7;
    const int s0 = ahalf * 2, s1 = s0 + 1;
    const int oh0 = ((s0       ^ ar7) << 4), ol0 = (((4 + s0) ^ ar7) << 4);
    const int oh1 = ((s1       ^ ar7) << 4), ol1 = (((4 + s1) ^ ar7) << 4);

    // ---- B staging mapping: issue i: row = (tid>>3)+32i, phys granule tid&7
    const int brow = tid >> 3, bg = tid & 7;
    const char* bhSrc = (const char*)Whs + (size_t)(n0 + brow) * 1024 + bg * 16;
    const char* btSrc = (const char*)Wts + (size_t)(n0 + brow) * 1024 + bg * 16;
    char* bhDst = (char*)Bh + brow * 128 + bg * 16;
    char* btDst = (char*)Bt + brow * 128 + bg * 16;

    f32x4 accH[4][4], accT[4][4];
#pragma unroll
    for (int i = 0; i < 4; ++i)
#pragma unroll
        for (int j = 0; j < 4; ++j) {
            accH[i][j] = (f32x4){0.f, 0.f, 0.f, 0.f};
            accT[i][j] = (f32x4){0.f, 0.f, 0.f, 0.f};
        }

    // preload A chunk 0 into regs
    f32x4 xg[4];
#pragma unroll
    for (int p = 0; p < 4; ++p) xg[p] = *(const f32x4*)(aSrc + p * 4);

    for (int c = 0; c < 8; ++c) {
        if (c) __syncthreads();          // prev chunk's frag reads done
        // B gloads first: latency hides under the A-split VALU below
        const int cb = c << 7;
#pragma unroll
        for (int i = 0; i < 4; ++i) {
            gload_lds16(bhSrc + (size_t)i * 32768 + cb, bhDst + i * 4096);
            gload_lds16(btSrc + (size_t)i * 32768 + cb, btDst + i * 4096);
        }
        // A split + LDS write (once per block, not per wave)
        {
            half8 hi0, lo0, hi1, lo1;
            split8(xg[0], xg[1], hi0, lo0);
            split8(xg[2], xg[3], hi1, lo1);
            *(half8*)(aDst + oh0) = hi0;
            *(half8*)(aDst + ol0) = lo0;
            *(half8*)(aDst + oh1) = hi1;
            *(half8*)(aDst + ol1) = lo1;
        }
        __syncthreads();                 // drains vmcnt+lgkm: tiles visible

        // prefetch next A chunk (latency hidden under MFMA block)
        if (c < 7) {
            const float* an = aSrc + (c + 1) * 32;
#pragma unroll
            for (int p = 0; p < 4; ++p) xg[p] = *(const f32x4*)(an + p * 4);
        }

        half8 ahh[4], ahl[4];
#pragma unroll
        for (int fi = 0; fi < 4; ++fi) {
            const int row = wm + fi * 16 + l15;
            const char* rb = (const char*)Ax + row * 128;
            ahh[fi] = *(const half8*)(rb + (((l4    ) ^ (row & 7)) << 4));
            ahl[fi] = *(const half8*)(rb + (((l4 + 4) ^ (row & 7)) << 4));
        }
#pragma unroll
        for (int j = 0; j < 4; ++j) {
            const int n = wn + j * 16 + l15;
            const int n7 = n & 7;
            const char* hr = (const char*)Bh + n * 128;
            const char* tr = (const char*)Bt + n * 128;
            const half8 bhh = *(const half8*)(hr + (((l4    ) ^ n7) << 4));
            const half8 bhl = *(const half8*)(hr + (((l4 + 4) ^ n7) << 4));
            const half8 bth = *(const half8*)(tr + (((l4    ) ^ n7) << 4));
            const half8 btl = *(const half8*)(tr + (((l4 + 4) ^ n7) << 4));
#pragma unroll
            for (int i = 0; i < 4; ++i) {
                accH[i][j] = __builtin_amdgcn_mfma_f32_16x16x32_f16(ahh[i], bhh, accH[i][j], 0, 0, 0);
                accH[i][j] = __builtin_amdgcn_mfma_f32_16x16x32_f16(ahh[i], bhl, accH[i][j], 0, 0, 0);
                accH[i][j] = __builtin_amdgcn_mfma_f32_16x16x32_f16(ahl[i], bhh, accH[i][j], 0, 0, 0);
                accT[i][j] = __builtin_amdgcn_mfma_f32_16x16x32_f16(ahh[i], bth, accT[i][j], 0, 0, 0);
                accT[i][j] = __builtin_amdgcn_mfma_f32_16x16x32_f16(ahh[i], btl, accT[i][j], 0, 0, 0);
                accT[i][j] = __builtin_amdgcn_mfma_f32_16x16x32_f16(ahl[i], bth, accT[i][j], 0, 0, 0);
            }
        }
    }

    // epilogue: C/D layout col = lane&15, row = (lane>>4)*4 + reg (m89)
    float bhv[4], btv[4];
#pragma unroll
    for (int j = 0; j < 4; ++j) {
        bhv[j] = bh[n0 + wn + j * 16 + l15];
        btv[j] = bt[n0 + wn + j * 16 + l15];
    }
#pragma unroll
    for (int i = 0; i < 4; ++i) {
        const int rbase = m0 + wm + i * 16 + l4 * 4;
#pragma unroll
        for (int rg = 0; rg < 4; ++rg) {
            const int gr = rbase + rg;
            if (gr < M) {
                float* dh = &Hout[(size_t)gr * EMB + n0 + wn];
                float* dt = &Tout[(size_t)gr * EMB + n0 + wn];
#pragma unroll
                for (int j = 0; j < 4; ++j) {
                    const int col = j * 16 + l15;
                    dh[col] = accH[i][j][rg] + bhv[j];
                    dt[col] = accT[i][j][rg] + btv[j];
                }
            }
        }
    }
}

// Two edges per wave: 6 outstanding row-gathers/wave for latency hiding.
__global__ __launch_bounds__(256)
void edge_score2(const float* __restrict__ H, const float* __restrict__ T,
                 const float* __restrict__ rel, const int* __restrict__ ei,
                 const int* __restrict__ et, float* __restrict__ out, int E)
{
    const int lane = threadIdx.x & 63;
    const int wid = threadIdx.x >> 6;
    const int e0 = (blockIdx.x * 4 + wid) * 2;
    if (e0 >= E) return;
    const bool two = (e0 + 1) < E;
    const int e1 = two ? e0 + 1 : e0;

    const int s0 = ei[e0], s1 = ei[e1];
    const int d0 = ei[E + e0], d1 = ei[E + e1];
    const int r0 = et[e0], r1 = et[e1];

    const int lo = lane * 4;
    const float4 h0 = *(const float4*)&H[(size_t)s0 * EMB + lo];
    const float4 h1 = *(const float4*)&H[(size_t)s1 * EMB + lo];
    const float4 t0 = *(const float4*)&T[(size_t)d0 * EMB + lo];
    const float4 t1 = *(const float4*)&T[(size_t)d1 * EMB + lo];
    const float4 g0 = *(const float4*)&rel[(size_t)r0 * EMB + lo];
    const float4 g1 = *(const float4*)&rel[(size_t)r1 * EMB + lo];

    float p0 = h0.x * g0.x * t0.x + h0.y * g0.y * t0.y
             + h0.z * g0.z * t0.z + h0.w * g0.w * t0.w;
    float p1 = h1.x * g1.x * t1.x + h1.y * g1.y * t1.y
             + h1.z * g1.z * t1.z + h1.w * g1.w * t1.w;
#pragma unroll
    for (int off = 32; off > 0; off >>= 1) {
        p0 += __shfl_xor(p0, off, 64);
        p1 += __shfl_xor(p1, off, 64);
    }
    if (lane == 0) {
        out[e0] = 1.0f / (1.0f + expf(-p0));
        if (two) out[e1] = 1.0f / (1.0f + expf(-p1));
    }
}

// Last-resort fallback: one block per edge, direct fp32 matvecs.
__global__ __launch_bounds__(256)
void edge_direct(const float* __restrict__ X, const int* __restrict__ ei,
                 const int* __restrict__ et,
                 const float* __restrict__ Wh, const float* __restrict__ bh,
                 const float* __restrict__ Wt, const float* __restrict__ bt,
                 const float* __restrict__ rel, float* __restrict__ out, int E)
{
    __shared__ float xsrc[EMB], xdst[EMB];
    __shared__ float red[256];
    const int e = blockIdx.x;
    const int tid = threadIdx.x;
    const int src = ei[e], dst = ei[E + e], r = et[e];

    xsrc[tid] = X[(size_t)src * EMB + tid];
    xdst[tid] = X[(size_t)dst * EMB + tid];
    __syncthreads();

    float ah = 0.f, at = 0.f;
    const float* wh = Wh + (size_t)tid * EMB;
    const float* wt = Wt + (size_t)tid * EMB;
#pragma unroll 8
    for (int k = 0; k < EMB; k += 4) {
        float4 w4 = *(const float4*)&wh[k];
        ah += w4.x * xsrc[k] + w4.y * xsrc[k + 1] + w4.z * xsrc[k + 2] + w4.w * xsrc[k + 3];
        float4 v4 = *(const float4*)&wt[k];
        at += v4.x * xdst[k] + v4.y * xdst[k + 1] + v4.z * xdst[k + 2] + v4.w * xdst[k + 3];
    }
    red[tid] = (ah + bh[tid]) * rel[(size_t)r * EMB + tid] * (at + bt[tid]);
    __syncthreads();
    for (int s2 = 128; s2 > 0; s2 >>= 1) {
        if (tid < s2) red[tid] += red[tid + s2];
        __syncthreads();
    }
    if (tid == 0) out[e] = 1.0f / (1.0f + expf(-red[0]));
}

extern "C" void kernel_launch(void* const* d_in, const int* in_sizes, int n_in,
                              void* d_out, int out_size, void* d_ws, size_t ws_size,
                              hipStream_t stream) {
    const float* x   = (const float*)d_in[0];
    const int*   ei  = (const int*)d_in[1];
    const int*   et  = (const int*)d_in[2];
    const float* Wh  = (const float*)d_in[3];
    const float* bh  = (const float*)d_in[4];
    const float* Wt  = (const float*)d_in[5];
    const float* bt  = (const float*)d_in[6];
    const float* rel = (const float*)d_in[7];
    float* out = (float*)d_out;

    const int M = in_sizes[0] / EMB;   // 100000 nodes
    const int E = in_sizes[2];         // 250000 edges

    const size_t szHT = (size_t)2 * M * EMB * sizeof(float);        // H + T
    const size_t szWs = (size_t)2 * 256 * 512 * sizeof(_Float16);   // Whs+Wts

    if (ws_size >= szHT + szWs) {
        float* H = (float*)d_ws;
        float* T = H + (size_t)M * EMB;
        _Float16* Whs = (_Float16*)((char*)d_ws + szHT);
        _Float16* Wts = Whs + (size_t)256 * 512;

        presplit_w<<<64, 256, 0, stream>>>(Wh, Wt, Whs, Wts);
        const int mtiles = (M + 127) / 128;
        const int nwg = 2 * mtiles;
        gemm_dual<<<nwg, 256, 0, stream>>>(x, Whs, Wts, bh, bt, H, T, M, nwg);
        edge_score2<<<(E + 7) / 8, 256, 0, stream>>>(H, T, rel, ei, et, out, E);
    } else {
        edge_direct<<<E, 256, 0, stream>>>(x, ei, et, Wh, bh, Wt, bt, rel, out, E);
    }
}